// Round 16
// baseline (26.882 us; speedup 1.0000x reference)
//
#include <hip/hip_runtime.h>

#define EPSF 1e-6f
#define TPB 256
#define KMAXC 21           // seg channels (K = 21)
#define RW 72              // bf16 row stride per wave d-slice (144 B; 16B-aligned frags)
#define SLICE (KMAXC * RW) // 1512 bf16 per wave (d only; mask goes direct to frags)
#define TBL 1024           // 32x32 scratch cells per block (LDS reduce only)
#define MAXBLK 1152

typedef float  f32x4  __attribute__((ext_vector_type(4)));
typedef float  f32x16 __attribute__((ext_vector_type(16)));
typedef __bf16 bf16x8 __attribute__((ext_vector_type(8)));

// pack two int !=0 flags into one dword of two bf16 (0.0 / 1.0)
__device__ __forceinline__ unsigned pk01(int lo, int hi) {
    return (lo != 0 ? 0x3F80u : 0u) | (hi != 0 ? 0x3F800000u : 0u);
}

__device__ __forceinline__ bf16x8 mask_frag(const int4& a, const int4& b) {
    union { unsigned w[4]; bf16x8 v; } u;
    u.w[0] = pk01(a.x, a.y);
    u.w[1] = pk01(a.z, a.w);
    u.w[2] = pk01(b.x, b.y);
    u.w[3] = pk01(b.z, b.w);
    return u.v;
}

// K1: A[k,g] = sum_n d[k,n]*gi[g,n], d = log2((s+eps)/(1-s+eps)) in bf16.
// Wave-private; mask B-fragments loaded directly from global in MFMA layout.
// Output layout is K-MAJOR: sums[(row*NBLK + block)*32 + col] so K2 streams
// one contiguous slab per k.
__global__ __launch_bounds__(TPB) void msk_main(
    const float* __restrict__ seg,   // (N, K) row-major
    const int* __restrict__ gt,      // (GROWS, N) row-major
    float* __restrict__ sums,        // K x NBLK x 32 f32, k-major
    int N, int K, int GROWS, int NGROUP, int NBLK)
{
    const int tid  = threadIdx.x;
    const int lane = tid & 63;
    const int wv   = tid >> 6;

    __shared__ union {
        __bf16 stage[4][SLICE];      // per-wave d rows [k][px]
        float  red[4 * TBL];
    } u;

    f32x16 acc = {};
    __bf16* dl = u.stage[wv];

    const int W  = NBLK * 4;
    const int gw = (int)blockIdx.x * 4 + wv;

    const int r31   = lane & 31;
    const int rowA  = (r31 < K) ? r31 : (K - 1);         // clamp: dup rows discarded
    const int rowM  = (r31 < GROWS) ? r31 : (GROWS - 1); // clamp: dup cols discarded
    const int half8 = (lane >> 5) << 3;
    const __bf16* pa = dl + rowA * RW + half8;

    for (int gid = gw; gid < NGROUP; gid += W) {
        const int p0 = gid << 6;
        bf16x8 bfrag[4];

        if (K == KMAXC && p0 + 64 <= N) {
            // ---- mask fragment loads: 8 int4 straight into MFMA B layout ----
            const int* gb = gt + (size_t)rowM * N + p0 + half8;
            const int4 m0 = *(const int4*)(gb +  0), m1 = *(const int4*)(gb +  4);
            const int4 m2 = *(const int4*)(gb + 16), m3 = *(const int4*)(gb + 20);
            const int4 m4 = *(const int4*)(gb + 32), m5 = *(const int4*)(gb + 36);
            const int4 m6 = *(const int4*)(gb + 48), m7 = *(const int4*)(gb + 52);

            // ---- seg loads: 6 coalesced f32x4 per lane ----
            f32x4 sreg[6];
            const f32x4* s4 = (const f32x4*)(seg + (size_t)p0 * KMAXC);
            #pragma unroll
            for (int q = 0; q < 6; ++q) {
                const int i4 = lane + (q << 6);          // f32x4 idx in [0,336)
                f32x4 v = {0.5f, 0.5f, 0.5f, 0.5f};
                if (i4 < 336) v = s4[i4];
                sreg[q] = v;
            }

            // convert mask while seg loads drain
            bfrag[0] = mask_frag(m0, m1);
            bfrag[1] = mask_frag(m2, m3);
            bfrag[2] = mask_frag(m4, m5);
            bfrag[3] = mask_frag(m6, m7);

            // ---- scatter d (log-odds, bf16) to this wave's LDS slice ----
            #pragma unroll
            for (int q = 0; q < 6; ++q) {
                const int i4 = lane + (q << 6);
                if (i4 < 336) {
                    const int lin = i4 << 2;
                    int pix = lin / KMAXC;
                    int k   = lin - pix * KMAXC;
                    #pragma unroll
                    for (int c = 0; c < 4; ++c) {
                        const float s = sreg[q][c];
                        const float dd = __log2f(s + EPSF) - __log2f(1.0f - s + EPSF);
                        dl[k * RW + pix] = (__bf16)dd;
                        if (++k == KMAXC) { k = 0; ++pix; }
                    }
                }
            }
        } else {
            // ---- generic fallback (tail group / odd K), correctness only ----
            for (int i = lane; i < K * 64; i += 64) {
                const int pix = i / K, k = i - pix * K;
                const float s = (p0 + pix < N) ? seg[(size_t)(p0 + pix) * K + k] : 0.5f;
                const float dd = __log2f(s + EPSF) - __log2f(1.0f - s + EPSF);
                if (k < KMAXC) dl[k * RW + pix] = (__bf16)dd;  // s=0.5 -> d=0 (inert)
            }
            #pragma unroll
            for (int i = 0; i < 4; ++i) {
                unsigned w[4];
                #pragma unroll
                for (int e = 0; e < 4; ++e) {
                    const int pA = p0 + 16 * i + half8 + 2 * e;
                    const int va = (pA < N) ? gt[(size_t)rowM * N + pA] : 0;
                    const int vb = (pA + 1 < N) ? gt[(size_t)rowM * N + pA + 1] : 0;
                    w[e] = pk01(va, vb);
                }
                union { unsigned ww[4]; bf16x8 v; } cvt;
                cvt.ww[0] = w[0]; cvt.ww[1] = w[1];
                cvt.ww[2] = w[2]; cvt.ww[3] = w[3];
                bfrag[i] = cvt.v;
            }
        }

        // ---- 4x MFMA over the 64-px group (K-dim = pixels) ----
        #pragma unroll
        for (int i = 0; i < 4; ++i) {
            const bf16x8 af = *(const bf16x8*)(pa + i * 16);
            acc = __builtin_amdgcn_mfma_f32_32x32x16_bf16(af, bfrag[i], acc, 0, 0, 0);
        }
    }

    // ---- cross-wave reduce via canonical LDS layout ----
    __syncthreads();
    {
        const int col = lane & 31;
        const int rhi = (lane >> 5) << 2;
        #pragma unroll
        for (int r = 0; r < 16; ++r) {
            const int row = (r & 3) + ((r >> 2) << 3) + rhi;   // verified C/D mapping
            u.red[wv * TBL + row * 32 + col] = acc[r];
        }
    }
    __syncthreads();

    // ---- k-major store: sums[(row*NBLK + bid)*32 + col]; coalesced 128-B
    //      segments; relaxed agent-scope atomic stores (plain stores proved
    //      unsafe cross-kernel under graph replay) ----
    {
        const int bid = (int)blockIdx.x;
        const int live = K * 32;             // 672 cells
        for (int cell = tid; cell < live; cell += TPB) {
            const int row = cell >> 5, col = cell & 31;
            const float v = u.red[cell] + u.red[TBL + cell]
                          + u.red[2 * TBL + cell] + u.red[3 * TBL + cell];
            __hip_atomic_store(&sums[((size_t)row * NBLK + bid) * 32 + col], v,
                               __ATOMIC_RELAXED, __HIP_MEMORY_SCOPE_AGENT);
        }
    }
}

// K2: block k streams its CONTIGUOUS slab sums[k*NBLK*32 ..] (NBLK*32 floats)
// with 1024 threads x predicated f32x4 loads, LDS-reduces per column, argmax.
__global__ __launch_bounds__(1024) void msk_final(
    const float* __restrict__ sums,
    const int* __restrict__ gpn,
    int* __restrict__ out,
    int K, int NBLK)
{
    const int G = *gpn;
    const int k = blockIdx.x;
    const int tid = threadIdx.x;

    const float* slab = sums + (size_t)k * NBLK * 32;
    const f32x4* slab4 = (const f32x4*)slab;
    const int nf4 = NBLK * 8;            // f32x4 count (9216 at NBLK=1152)

    f32x4 a4 = {0.f, 0.f, 0.f, 0.f};
    #pragma unroll
    for (int i = 0; i < 16; ++i) {       // covers NBLK <= 2048; loads independent
        const int idx = tid + (i << 10);
        if (idx < nf4) {
            const float* p = (const float*)(slab4 + idx);
            f32x4 v;
            v.x = __hip_atomic_load(p + 0, __ATOMIC_RELAXED, __HIP_MEMORY_SCOPE_AGENT);
            v.y = __hip_atomic_load(p + 1, __ATOMIC_RELAXED, __HIP_MEMORY_SCOPE_AGENT);
            v.z = __hip_atomic_load(p + 2, __ATOMIC_RELAXED, __HIP_MEMORY_SCOPE_AGENT);
            v.w = __hip_atomic_load(p + 3, __ATOMIC_RELAXED, __HIP_MEMORY_SCOPE_AGENT);
            a4 += v;
        }
    }

    // thread t covers cols 4q..4q+3 (q = t&7) for block-slot b0 = t>>3
    const int q  = tid & 7;
    const int b0 = tid >> 3;             // 0..127

    __shared__ float Pr[128][36];
    __shared__ float A[32];
    *(f32x4*)&Pr[b0][q << 2] = a4;
    __syncthreads();

    if (tid < 32) {
        float s = 0.f;
        for (int b = 0; b < 128; ++b) s += Pr[b][tid];
        A[tid] = s;
    }
    __syncthreads();

    if (tid == 0) {
        const int GG = (G < 32) ? G : 32;
        float bv; int bg = 0;
        if (GG > 0) {
            bv = A[0];
            for (int g = 1; g < GG; ++g) {
                const float v = A[g];
                if (v > bv) { bv = v; bg = g; }   // strict '>' keeps first index
            }
        }
        out[k] = bg;
    }
}

extern "C" void kernel_launch(void* const* d_in, const int* in_sizes, int n_in,
                              void* d_out, int out_size, void* d_ws, size_t ws_size,
                              hipStream_t stream) {
    const float* seg = (const float*)d_in[0];
    // d_in[1] (prob) does not affect the reference output
    const int* gt  = (const int*)d_in[2];
    const int* gpn = (const int*)d_in[3];

    const int N = in_sizes[1];              // prob is (N,1)
    const int K = in_sizes[0] / N;          // 21
    const int GROWS = in_sizes[2] / N;      // 21
    const int NGROUP = (N + 63) >> 6;       // 4800 64-px groups

    int NBLK = MAXBLK;                      // 1152: wraparound absorbs last 192
    const int minb = (NGROUP + 3) >> 2;
    if (NBLK > minb) NBLK = minb;
    const long long wcap =
        (long long)(ws_size / ((size_t)(K > 0 ? K : 1) * 32 * sizeof(float)));
    if (NBLK > wcap) NBLK = (int)wcap;      // d_ws budget (observed ~256 MB)
    if (NBLK > 2048) NBLK = 2048;           // K2 unroll coverage
    if (NBLK < 1) NBLK = 1;

    msk_main <<<NBLK, TPB, 0, stream>>>(seg, gt, (float*)d_ws,
                                        N, K, GROWS, NGROUP, NBLK);
    msk_final<<<K, 1024, 0, stream>>>((const float*)d_ws, gpn, (int*)d_out,
                                      K, NBLK);
}

// Round 17
// 21.152 us; speedup vs baseline: 1.2709x; 1.2709x over previous
//
#include <hip/hip_runtime.h>

#define EPSF 1e-6f
#define TPB 256
#define KMAXC 21           // seg channels (K = 21)
#define RW 72              // bf16 row stride per wave d-slice (144 B; 16B-aligned frags)
#define SLICE (KMAXC * RW) // 1512 bf16 per wave (d only; mask goes direct to frags)
#define TBL 1024           // 32x32 cells per per-block table (4 KB stride)
#define MAXBLK 1200        // exactly one 64-px group per wave (no wraparound tail)

typedef float  f32x4  __attribute__((ext_vector_type(4)));
typedef float  f32x16 __attribute__((ext_vector_type(16)));
typedef __bf16 bf16x8 __attribute__((ext_vector_type(8)));

// pack two int !=0 flags into one dword of two bf16 (0.0 / 1.0)
__device__ __forceinline__ unsigned pk01(int lo, int hi) {
    return (lo != 0 ? 0x3F80u : 0u) | (hi != 0 ? 0x3F800000u : 0u);
}

__device__ __forceinline__ bf16x8 mask_frag(const int4& a, const int4& b) {
    union { unsigned w[4]; bf16x8 v; } u;
    u.w[0] = pk01(a.x, a.y);
    u.w[1] = pk01(a.z, a.w);
    u.w[2] = pk01(b.x, b.y);
    u.w[3] = pk01(b.z, b.w);
    return u.v;
}

// K1: A[k,g] = sum_n d[k,n]*gi[g,n], d = log2((s+eps)/(1-s+eps)) in bf16.
// Wave-private; mask B-fragments loaded DIRECTLY from global in MFMA layout
// (no mask LDS); per-block private output tables (no RMW, no zero-init).
__global__ __launch_bounds__(TPB) void msk_main(
    const float* __restrict__ seg,   // (N, K) row-major
    const int* __restrict__ gt,      // (GROWS, N) row-major
    float* __restrict__ sums,        // NBLK x [TBL] f32 per-block tables
    int N, int K, int GROWS, int NGROUP, int NBLK)
{
    const int tid  = threadIdx.x;
    const int lane = tid & 63;
    const int wv   = tid >> 6;

    __shared__ union {
        __bf16 stage[4][SLICE];      // per-wave d rows [k][px]
        float  red[4 * TBL];
    } u;

    f32x16 acc = {};
    __bf16* dl = u.stage[wv];

    const int W  = NBLK * 4;
    const int gw = (int)blockIdx.x * 4 + wv;

    const int r31   = lane & 31;
    const int rowA  = (r31 < K) ? r31 : (K - 1);         // clamp: dup rows discarded
    const int rowM  = (r31 < GROWS) ? r31 : (GROWS - 1); // clamp: dup cols discarded
    const int half8 = (lane >> 5) << 3;
    const __bf16* pa = dl + rowA * RW + half8;

    for (int gid = gw; gid < NGROUP; gid += W) {
        const int p0 = gid << 6;
        bf16x8 bfrag[4];

        if (K == KMAXC && p0 + 64 <= N) {
            // ---- mask fragment loads: 8 int4 straight into MFMA B layout ----
            const int* gb = gt + (size_t)rowM * N + p0 + half8;
            const int4 m0 = *(const int4*)(gb +  0), m1 = *(const int4*)(gb +  4);
            const int4 m2 = *(const int4*)(gb + 16), m3 = *(const int4*)(gb + 20);
            const int4 m4 = *(const int4*)(gb + 32), m5 = *(const int4*)(gb + 36);
            const int4 m6 = *(const int4*)(gb + 48), m7 = *(const int4*)(gb + 52);

            // ---- seg loads: 6 coalesced f32x4 per lane ----
            f32x4 sreg[6];
            const f32x4* s4 = (const f32x4*)(seg + (size_t)p0 * KMAXC);
            #pragma unroll
            for (int q = 0; q < 6; ++q) {
                const int i4 = lane + (q << 6);          // f32x4 idx in [0,336)
                f32x4 v = {0.5f, 0.5f, 0.5f, 0.5f};
                if (i4 < 336) v = s4[i4];
                sreg[q] = v;
            }

            // convert mask while seg loads drain
            bfrag[0] = mask_frag(m0, m1);
            bfrag[1] = mask_frag(m2, m3);
            bfrag[2] = mask_frag(m4, m5);
            bfrag[3] = mask_frag(m6, m7);

            // ---- scatter d (log-odds, bf16) to this wave's LDS slice ----
            #pragma unroll
            for (int q = 0; q < 6; ++q) {
                const int i4 = lane + (q << 6);
                if (i4 < 336) {
                    const int lin = i4 << 2;
                    int pix = lin / KMAXC;
                    int k   = lin - pix * KMAXC;
                    #pragma unroll
                    for (int c = 0; c < 4; ++c) {
                        const float s = sreg[q][c];
                        const float dd = __log2f(s + EPSF) - __log2f(1.0f - s + EPSF);
                        dl[k * RW + pix] = (__bf16)dd;
                        if (++k == KMAXC) { k = 0; ++pix; }
                    }
                }
            }
        } else {
            // ---- generic fallback (tail group / odd K), correctness only ----
            for (int i = lane; i < K * 64; i += 64) {
                const int pix = i / K, k = i - pix * K;
                const float s = (p0 + pix < N) ? seg[(size_t)(p0 + pix) * K + k] : 0.5f;
                const float dd = __log2f(s + EPSF) - __log2f(1.0f - s + EPSF);
                if (k < KMAXC) dl[k * RW + pix] = (__bf16)dd;  // s=0.5 -> d=0 (inert)
            }
            #pragma unroll
            for (int i = 0; i < 4; ++i) {
                unsigned w[4];
                #pragma unroll
                for (int e = 0; e < 4; ++e) {
                    const int pA = p0 + 16 * i + half8 + 2 * e;
                    const int va = (pA < N) ? gt[(size_t)rowM * N + pA] : 0;
                    const int vb = (pA + 1 < N) ? gt[(size_t)rowM * N + pA + 1] : 0;
                    w[e] = pk01(va, vb);
                }
                union { unsigned ww[4]; bf16x8 v; } cvt;
                cvt.ww[0] = w[0]; cvt.ww[1] = w[1];
                cvt.ww[2] = w[2]; cvt.ww[3] = w[3];
                bfrag[i] = cvt.v;
            }
        }

        // ---- 4x MFMA over the 64-px group (K-dim = pixels) ----
        #pragma unroll
        for (int i = 0; i < 4; ++i) {
            const bf16x8 af = *(const bf16x8*)(pa + i * 16);
            acc = __builtin_amdgcn_mfma_f32_32x32x16_bf16(af, bfrag[i], acc, 0, 0, 0);
        }
    }

    // ---- cross-wave reduce via canonical LDS layout ----
    __syncthreads();
    {
        const int col = lane & 31;
        const int rhi = (lane >> 5) << 2;
        #pragma unroll
        for (int r = 0; r < 16; ++r) {
            const int row = (r & 3) + ((r >> 2) << 3) + rhi;   // verified C/D mapping
            u.red[wv * TBL + row * 32 + col] = acc[r];
        }
    }
    __syncthreads();

    // ---- private table write: live rows only (rows >= K never read by K2);
    //      relaxed agent-scope atomic stores (plain stores proved unsafe
    //      cross-kernel under graph replay) ----
    {
        float* stbl = sums + (size_t)blockIdx.x * TBL;
        const int live = K * 32;             // 672 cells
        for (int cell = tid; cell < live; cell += TPB) {
            const float v = u.red[cell] + u.red[TBL + cell]
                          + u.red[2 * TBL + cell] + u.red[3 * TBL + cell];
            __hip_atomic_store(&stbl[cell], v, __ATOMIC_RELAXED,
                               __HIP_MEMORY_SCOPE_AGENT);
        }
    }
}

// K2: block k reduces its row across all NBLK tables. 1024 threads, 32 table-
// groups; each group owns a CONTIGUOUS run of NBLK/32 tables walked with 8
// independent accumulator streams and unconditional affine loads.
__global__ __launch_bounds__(1024) void msk_final(
    const float* __restrict__ sums,
    const int* __restrict__ gpn,
    int* __restrict__ out,
    int K, int NBLK)
{
    const int G = *gpn;
    const int k = blockIdx.x;
    const int tid = threadIdx.x;
    const int col = tid & 31;
    const int grp = tid >> 5;            // 0..31 table-groups

    const int tpg = NBLK >> 5;           // tables per group (37 at NBLK=1200)
    const int t0  = grp * tpg;
    const size_t rowoff = (size_t)k * 32 + col;

    #define AL(T) __hip_atomic_load(&sums[(size_t)(T) * TBL + rowoff], \
                                    __ATOMIC_RELAXED, __HIP_MEMORY_SCOPE_AGENT)
    float v0 = 0.f, v1 = 0.f, v2 = 0.f, v3 = 0.f;
    float v4 = 0.f, v5 = 0.f, v6 = 0.f, v7 = 0.f;
    int i = 0;
    for (; i + 8 <= tpg; i += 8) {       // unconditional: 8 loads in flight
        v0 += AL(t0 + i + 0); v1 += AL(t0 + i + 1);
        v2 += AL(t0 + i + 2); v3 += AL(t0 + i + 3);
        v4 += AL(t0 + i + 4); v5 += AL(t0 + i + 5);
        v6 += AL(t0 + i + 6); v7 += AL(t0 + i + 7);
    }
    for (; i < tpg; ++i) v0 += AL(t0 + i);
    // leftover tables beyond 32*tpg (NBLK % 32 of them)
    if (grp < (NBLK & 31)) v1 += AL((NBLK & ~31) + grp);
    #undef AL
    const float vv = ((v0 + v1) + (v2 + v3)) + ((v4 + v5) + (v6 + v7));

    __shared__ float P[32][33];
    __shared__ float A[32];
    P[grp][col] = vv;
    __syncthreads();
    if (tid < 32) {
        float s = 0.f;
        #pragma unroll
        for (int g2 = 0; g2 < 32; ++g2) s += P[g2][tid];
        A[tid] = s;
    }
    __syncthreads();

    if (tid == 0) {
        const int GG = (G < 32) ? G : 32;
        float bv; int bg = 0;
        if (GG > 0) {
            bv = A[0];
            for (int g = 1; g < GG; ++g) {
                const float v = A[g];
                if (v > bv) { bv = v; bg = g; }   // strict '>' keeps first index
            }
        }
        out[k] = bg;
    }
}

extern "C" void kernel_launch(void* const* d_in, const int* in_sizes, int n_in,
                              void* d_out, int out_size, void* d_ws, size_t ws_size,
                              hipStream_t stream) {
    const float* seg = (const float*)d_in[0];
    // d_in[1] (prob) does not affect the reference output
    const int* gt  = (const int*)d_in[2];
    const int* gpn = (const int*)d_in[3];

    const int N = in_sizes[1];              // prob is (N,1)
    const int K = in_sizes[0] / N;          // 21
    const int GROWS = in_sizes[2] / N;      // 21
    const int NGROUP = (N + 63) >> 6;       // 4800 64-px groups

    int NBLK = MAXBLK;                      // 1200: exactly 1 group per wave
    const int minb = (NGROUP + 3) >> 2;
    if (NBLK > minb) NBLK = minb;
    const long long wcap = (long long)(ws_size / (TBL * sizeof(float)));
    if (NBLK > wcap) NBLK = (int)wcap;      // d_ws budget (observed ~256 MB)
    if (NBLK < 1) NBLK = 1;

    msk_main <<<NBLK, TPB, 0, stream>>>(seg, gt, (float*)d_ws,
                                        N, K, GROWS, NGROUP, NBLK);
    msk_final<<<K, 1024, 0, stream>>>((const float*)d_ws, gpn, (int*)d_out,
                                      K, NBLK);
}